// Round 8
// baseline (374.330 us; speedup 1.0000x reference)
//
#include <hip/hip_runtime.h>

typedef __attribute__((ext_vector_type(8))) short bf16x8;
typedef __attribute__((ext_vector_type(4))) short bf16x4;
typedef __attribute__((ext_vector_type(4))) float f32x4;
typedef __attribute__((ext_vector_type(2))) float f32x2;

static __device__ __forceinline__ f32x4 MFMA_QK(bf16x8 a, bf16x8 b, f32x4 c) {
  return __builtin_amdgcn_mfma_f32_16x16x32_bf16(a, b, c, 0, 0, 0);
}

#if __has_builtin(__builtin_amdgcn_mfma_f32_16x16x16bf16_1k)
static __device__ __forceinline__ f32x4 MFMA_PV(bf16x4 a, bf16x4 b, f32x4 c) {
  return __builtin_amdgcn_mfma_f32_16x16x16bf16_1k(a, b, c, 0, 0, 0);
}
#define PV_EPILOGUE_GUARD()
#else
static __device__ __forceinline__ f32x4 MFMA_PV(bf16x4 a, bf16x4 b, f32x4 c) {
  asm("v_mfma_f32_16x16x16_bf16 %0, %1, %2, %0" : "+v"(c) : "v"(a), "v"(b));
  return c;
}
#define PV_EPILOGUE_GUARD() asm volatile("s_nop 7\ns_nop 7" :::)
#endif

#if __has_builtin(__builtin_amdgcn_exp2f)
#define EXP2(x) __builtin_amdgcn_exp2f(x)
#else
#define EXP2(x) exp2f(x)
#endif

#define NB   2
#define NSEQ 2048
#define NH   8
#define ND   64
#define FIN  512
#define MD   512
#define NTOK (NB * NSEQ)
#define SCALE_LOG2E 0.18033688011112042f   // (1/sqrt(64)) * log2(e)

#define XB_ELEMS   (NTOK * FIN)            // 2097152 bf16
#define WT_ELEMS   (MD * FIN)              // 262144 bf16
#define HH_ELEMS   (NB * NH * NSEQ * ND)   // 2097152 bf16 (h_c / h_v each)
#define MB_ELEMS   (NTOK * 32)             // 131072 u64 (bit-packed adj)
#define L_ELEMS    (NB * NH * NSEQ)        // 32768 fp32 per partial
#define O_ELEMS    (NTOK * MD)             // 2097152 f32 (single accumulator)
#define NSPLIT_S   8
#define NSPLIT_A   8

static __device__ __forceinline__ unsigned short f2b(float f) {
  union { float f; unsigned u; } c; c.f = f;
  unsigned u = c.u;
  u += 0x7fffu + ((u >> 16) & 1u);   // RNE; inputs finite
  return (unsigned short)(u >> 16);
}

static __device__ __forceinline__ unsigned pack2(float a, float b) {
#if __has_builtin(__builtin_amdgcn_cvt_pk_bf16_f32)
  auto v = __builtin_amdgcn_cvt_pk_bf16_f32(a, b);
  unsigned r; __builtin_memcpy(&r, &v, 4); return r;
#else
  return (unsigned)f2b(a) | ((unsigned)f2b(b) << 16);
#endif
}

static __device__ __forceinline__ void split8(bf16x8 v, bf16x4* a, bf16x4* b) {
  union { bf16x8 w; bf16x4 h[2]; } u; u.w = v; *a = u.h[0]; *b = u.h[1];
}

// ============================================================================
// Convert x -> bf16 (xb) and W -> bf16 transposed (wt[n][k]).
// ============================================================================
__global__ __launch_bounds__(256)
void cvt_kernel(const float* __restrict__ x, const float* __restrict__ W,
                unsigned short* __restrict__ xb, unsigned short* __restrict__ wt) {
  const int t = threadIdx.x;
  if (blockIdx.x < 2048) {
    size_t i = ((size_t)blockIdx.x * 256 + t) * 4;
    f32x4 v = *(const f32x4*)(x + i);
    ushort4 o = make_ushort4(f2b(v[0]), f2b(v[1]), f2b(v[2]), f2b(v[3]));
    *(ushort4*)(xb + i) = o;
  } else {
    int j = ((int)(blockIdx.x - 2048) * 256 + t) * 4;
    int k = j >> 9, n = j & 511;
    f32x4 v = *(const f32x4*)(W + (size_t)k * MD + n);
    wt[(size_t)(n + 0) * FIN + k] = f2b(v[0]);
    wt[(size_t)(n + 1) * FIN + k] = f2b(v[1]);
    wt[(size_t)(n + 2) * FIN + k] = f2b(v[2]);
    wt[(size_t)(n + 3) * FIN + k] = f2b(v[3]);
  }
}

// ============================================================================
// Bit-pack adj: mb[row*32 + w] = ballot(adj[row][w*64 + lane] != 0).
// ============================================================================
__global__ __launch_bounds__(1024)
void maskpack_kernel(const int* __restrict__ adj, unsigned long long* __restrict__ mb) {
  const int t = threadIdx.x;
  const int gw = blockIdx.x * 16 + (t >> 6);     // gw = row*32 + w64
  const int row = gw >> 5, w64 = gw & 31;
  int a = adj[(size_t)row * NSEQ + w64 * 64 + (t & 63)];
  unsigned long long m = __ballot(a != 0);
  if ((t & 63) == 0) mb[gw] = m;
}

// ============================================================================
// Projection GEMM -> h in MFMA-fragment layouts. Dual accumulators:
//  acc_v = MFMA(af, bf): lane holds 4 consecutive TOKENS for fixed d -> h_v
//  acc_c = MFMA(bf, af): lane holds 4 consecutive D for fixed token -> h_c
// Both epilogues are pure ushort4 stores (no scalar scatter).
// ============================================================================
__global__ __launch_bounds__(256, 2)
void proj_kernel(const unsigned short* __restrict__ xb, const unsigned short* __restrict__ wt,
                 const float* __restrict__ bias,
                 unsigned short* __restrict__ h_c, unsigned short* __restrict__ h_v) {
  __shared__ __align__(16) unsigned short sA[64][72];
  __shared__ __align__(16) unsigned short sB[64][72];
  const int t = threadIdx.x;
  const int w = t >> 6, L = t & 63, l15 = L & 15, qd = L >> 4;
  const int bm = blockIdx.x, bn = blockIdx.y;
  const int r = t >> 3, c8 = (t & 7) * 8;
  const f32x4 ZERO4 = {0.f, 0.f, 0.f, 0.f};

  f32x4 acc_v[4], acc_c[4];
  #pragma unroll
  for (int q = 0; q < 4; ++q) { acc_v[q] = ZERO4; acc_c[q] = ZERO4; }

  for (int ks = 0; ks < FIN; ks += 64) {
    __syncthreads();
    *(bf16x8*)&sA[r][c8]      = *(const bf16x8*)&xb[(size_t)(bm*64 + r)      * FIN + ks + c8];
    *(bf16x8*)&sA[r + 32][c8] = *(const bf16x8*)&xb[(size_t)(bm*64 + r + 32) * FIN + ks + c8];
    *(bf16x8*)&sB[r][c8]      = *(const bf16x8*)&wt[(size_t)(bn*64 + r)      * FIN + ks + c8];
    *(bf16x8*)&sB[r + 32][c8] = *(const bf16x8*)&wt[(size_t)(bn*64 + r + 32) * FIN + ks + c8];
    __syncthreads();
    #pragma unroll
    for (int kk = 0; kk < 2; ++kk) {
      bf16x8 af = *(const bf16x8*)&sA[16*w + l15][kk*32 + qd*8];
      #pragma unroll
      for (int q = 0; q < 4; ++q) {
        bf16x8 bf = *(const bf16x8*)&sB[16*q + l15][kk*32 + qd*8];
        acc_v[q] = MFMA_QK(af, bf, acc_v[q]);
        acc_c[q] = MFMA_QK(bf, af, acc_c[q]);
      }
    }
  }

  const int head = bn;
  const int b0 = bm >> 5;
  const int nloc = (bm & 31) * 64;               // token base within batch b0
  const size_t slab = (size_t)(b0 * NH + head) * ((size_t)NSEQ * ND);

  // h_v: acc_v[q][rr] = h[token = nloc+16w+qd*4+rr][d = 16q+l15]
  #pragma unroll
  for (int q = 0; q < 4; ++q) {
    int d = 16*q + l15;
    float bv = bias[bn*64 + d];
    unsigned short pk[4];
    #pragma unroll
    for (int rr = 0; rr < 4; ++rr) pk[rr] = f2b(acc_v[q][rr] + bv);
    int n0 = nloc + 16*w + qd*4;
    size_t vidx = slab + (size_t)(n0 >> 4) * 1024 + (size_t)(d >> 5) * 512
                + (size_t)((((n0 >> 2) & 3) * 16 + (d & 15)) * 8) + (size_t)(((d >> 4) & 1) * 4);
    *(ushort4*)&h_v[vidx] = make_ushort4(pk[0], pk[1], pk[2], pk[3]);
  }
  // h_c: acc_c[q][rr] = h[token = nloc+16w+l15][d = 16q+4qd+rr]
  #pragma unroll
  for (int q = 0; q < 4; ++q) {
    int dbase = 16*q + 4*qd;
    f32x4 bv4 = *(const f32x4*)&bias[bn*64 + dbase];
    unsigned short pk[4];
    #pragma unroll
    for (int rr = 0; rr < 4; ++rr) pk[rr] = f2b(acc_c[q][rr] + bv4[rr]);
    int n = nloc + 16*w + l15;
    size_t cidx = slab + (size_t)(n >> 4) * 1024 + (size_t)(q >> 1) * 512
                + (size_t)(((dbase >> 3) & 3) * 128) + (size_t)((n & 15) * 8) + (size_t)(dbase & 7);
    *(ushort4*)&h_c[cidx] = make_ushort4(pk[0], pk[1], pk[2], pk[3]);
  }
}

// ============================================================================
// Stats: l_part[e][b][h][n] = sum over column-eighth e of mask*exp(s/8).
// No LDS, no barriers; all loads lane-contiguous from h_c. Grid (128,8).
// ============================================================================
__global__ __launch_bounds__(512, 4)
void stats_kernel(const unsigned short* __restrict__ h_c,
                  const unsigned long long* __restrict__ mb,
                  float* __restrict__ l_part) {
  const int t = threadIdx.x;
  const int h = t >> 6, L = t & 63, l15 = L & 15, qd = L >> 4;
  const int u = blockIdx.x & 7;
  const int b = u >> 2;
  const int rblk = ((int)blockIdx.x >> 3) * 4 + (u & 3);
  const int q8 = blockIdx.y;
  const int n0 = rblk * 32;
  const int qd4 = qd * 4;
  const int lane8 = L * 8;
  const f32x4 ZERO4 = {0.f, 0.f, 0.f, 0.f};

  const unsigned short* hc = h_c + (size_t)(b * NH + h) * (NSEQ * ND);
  bf16x8 qf[2][2];
  #pragma unroll
  for (int g = 0; g < 2; ++g)
    #pragma unroll
    for (int kk = 0; kk < 2; ++kk)
      qf[g][kk] = *(const bf16x8*)&hc[((n0 >> 4) + g) * 1024 + kk * 512 + lane8];

  float lacc[2] = {0.f, 0.f};
  const unsigned long long* mrow = mb + (((size_t)(b * NSEQ + n0 + l15)) << 5) + q8 * 4;

  for (int it = 0; it < 4; ++it) {
    const int c0 = q8 * 256 + it * 64;
    unsigned mlo[2], mhi[2];
    #pragma unroll
    for (int g = 0; g < 2; ++g) {
      unsigned long long m = mrow[g * 512 + it];   // row += 16 -> +512 u64
      mlo[g] = (unsigned)m; mhi[g] = (unsigned)(m >> 32);
    }
    #pragma unroll
    for (int cc = 0; cc < 4; ++cc) {
      const int cb = (c0 >> 4) + cc;
      bf16x8 kf0 = *(const bf16x8*)&hc[cb * 1024 + lane8];
      bf16x8 kf1 = *(const bf16x8*)&hc[cb * 1024 + 512 + lane8];
      #pragma unroll
      for (int g = 0; g < 2; ++g) {
        f32x4 s = MFMA_QK(kf0, qf[g][0], ZERO4);
        s = MFMA_QK(kf1, qf[g][1], s);
        unsigned nib = (((cc & 2) ? mhi[g] : mlo[g]) >> (((cc & 1) << 4) + qd4)) & 0xFu;
        #pragma unroll
        for (int rr = 0; rr < 4; ++rr) {
          float e = EXP2(s[rr] * SCALE_LOG2E);
          lacc[g] += (nib & (1u << rr)) ? e : 0.f;
        }
      }
    }
  }
  #pragma unroll
  for (int g = 0; g < 2; ++g) {
    float v = lacc[g];
    v += __shfl_xor(v, 16);
    v += __shfl_xor(v, 32);
    if (L < 16)
      l_part[(size_t)q8 * L_ELEMS + (size_t)(b * NH + h) * NSEQ + n0 + g*16 + L] = v;
  }
}

// ============================================================================
// Attention: 32 rows x 256 cols per block, 8 waves = 8 heads.
// Grid (128,8) = 1024 blocks = 4 blocks/CU (LDS 36.9 KB, VGPR <= 64 target).
// O accumulated into a single fp32 buffer via atomicAdd (memset before launch).
// launch_bounds (512,4): VGPR cap 128 (r4 lesson: never demand 8 waves/EU).
// ============================================================================
__global__ __launch_bounds__(512, 4)
void attn_kernel(const unsigned short* __restrict__ h_c, const unsigned short* __restrict__ h_v,
                 const unsigned long long* __restrict__ mb, const float* __restrict__ l_part,
                 float* __restrict__ o_acc, float* __restrict__ mean_out) {
  const int t = threadIdx.x;
  const int h = t >> 6, L = t & 63, l15 = L & 15, qd = L >> 4;
  const int u = blockIdx.x & 7;
  const int b = u >> 2;
  const int rblk = ((int)blockIdx.x >> 3) * 4 + (u & 3);
  const int eighth = blockIdx.y;
  const int n0 = rblk * 32;
  const int qd4 = qd * 4;
  const int lane8 = L * 8;
  __shared__ __align__(16) unsigned short s_part[8][32][72];   // 36864 B
  const f32x4 ZERO4 = {0.f, 0.f, 0.f, 0.f};

  const unsigned short* hc = h_c + (size_t)(b * NH + h) * (NSEQ * ND);
  const unsigned short* hv = h_v + (size_t)(b * NH + h) * (NSEQ * ND);

  bf16x8 qf[2][2];
  #pragma unroll
  for (int g = 0; g < 2; ++g)
    #pragma unroll
    for (int kk = 0; kk < 2; ++kk)
      qf[g][kk] = *(const bf16x8*)&hc[((n0 >> 4) + g) * 1024 + kk * 512 + lane8];

  float linv[2];
  #pragma unroll
  for (int g = 0; g < 2; ++g) {
    size_t idx = (size_t)(b * NH + h) * NSEQ + n0 + g*16 + l15;
    float ls = 0.f;
    #pragma unroll
    for (int q = 0; q < NSPLIT_S; ++q) ls += l_part[(size_t)q * L_ELEMS + idx];
    linv[g] = -__log2f(ls);
  }

  f32x4 oacc[2][4];
  #pragma unroll
  for (int g = 0; g < 2; ++g)
    #pragma unroll
    for (int dc = 0; dc < 4; ++dc) oacc[g][dc] = ZERO4;

  const int cr = t >> 4, cc4 = (t & 15) * 4;
  const unsigned long long* mrow = mb + (((size_t)(b * NSEQ + n0 + l15)) << 5) + eighth * 4;

  for (int it = 0; it < 4; ++it) {
    const int c0 = eighth * 256 + it * 64;
    unsigned mlo[2], mhi[2];
    #pragma unroll
    for (int g = 0; g < 2; ++g) {
      unsigned long long m = mrow[g * 512 + it];
      mlo[g] = (unsigned)m; mhi[g] = (unsigned)(m >> 32);
    }
    __syncthreads();   // A: previous iter's mean reads of s_part complete
    #pragma unroll
    for (int cc = 0; cc < 4; ++cc) {
      const int cb = (c0 >> 4) + cc;
      bf16x8 kf0 = *(const bf16x8*)&hc[cb * 1024 + lane8];
      bf16x8 kf1 = *(const bf16x8*)&hc[cb * 1024 + 512 + lane8];
      bf16x8 vv0 = *(const bf16x8*)&hv[cb * 1024 + lane8];
      bf16x8 vv1 = *(const bf16x8*)&hv[cb * 1024 + 512 + lane8];
      bf16x4 va[4];
      split8(vv0, &va[0], &va[1]);
      split8(vv1, &va[2], &va[3]);
      #pragma unroll
      for (int g = 0; g < 2; ++g) {
        f32x4 s = MFMA_QK(kf0, qf[g][0], ZERO4);
        s = MFMA_QK(kf1, qf[g][1], s);
        unsigned nib = (((cc & 2) ? mhi[g] : mlo[g]) >> (((cc & 1) << 4) + qd4)) & 0xFu;
        f32x4 p;
        #pragma unroll
        for (int rr = 0; rr < 4; ++rr) {
          float e = EXP2(__builtin_fmaf(s[rr], SCALE_LOG2E, linv[g]));
          p[rr] = (nib & (1u << rr)) ? e : 0.f;
        }
        union { unsigned u2[2]; bf16x4 v4; uint2 d; } pk;
        pk.u2[0] = pack2(p[0], p[1]);
        pk.u2[1] = pack2(p[2], p[3]);
        *(uint2*)&s_part[h][g*16 + l15][cc*16 + qd4] = pk.d;
        #pragma unroll
        for (int dc = 0; dc < 4; ++dc)
          oacc[g][dc] = MFMA_PV(va[dc], pk.v4, oacc[g][dc]);
      }
    }
    __syncthreads();   // C: s_part complete
    {
      f32x4 macc = ZERO4;
      #pragma unroll
      for (int hh = 0; hh < 8; ++hh) {
        uint2 pv = *(const uint2*)&s_part[hh][cr][cc4];
        union { unsigned u; float f; } a0, a1, a2, a3;
        a0.u = pv.x << 16; a1.u = pv.x & 0xffff0000u;
        a2.u = pv.y << 16; a3.u = pv.y & 0xffff0000u;
        macc[0] += a0.f; macc[1] += a1.f; macc[2] += a2.f; macc[3] += a3.f;
      }
      macc *= 0.125f;
      *(f32x4*)&mean_out[((size_t)b * NSEQ + n0 + cr) * NSEQ + c0 + cc4] = macc;
    }
  }

  PV_EPILOGUE_GUARD();
  #pragma unroll
  for (int g = 0; g < 2; ++g)
    #pragma unroll
    for (int dc = 0; dc < 4; ++dc) {
      size_t token = (size_t)b * NSEQ + n0 + g*16 + l15;
      float* dst = &o_acc[token * MD + h*64 + dc*16 + qd4];
      #pragma unroll
      for (int rr = 0; rr < 4; ++rr) atomicAdd(dst + rr, oacc[g][dc][rr]);
    }
}

// ============================================================================
// LayerNorm over model dim; reads the single fp32 O accumulator.
// ============================================================================
__global__ __launch_bounds__(256)
void ln_kernel(const float* __restrict__ o_acc, const float* __restrict__ gamma,
               const float* __restrict__ beta, float* __restrict__ out) {
  const int row = blockIdx.x, t = threadIdx.x;
  const size_t base = (size_t)row * MD + 2 * t;
  f32x2 x = *(const f32x2*)&o_acc[base];
  float v0 = x[0], v1 = x[1];
  float s = v0 + v1, sq = v0 * v0 + v1 * v1;
  for (int m = 1; m < 64; m <<= 1) { s += __shfl_xor(s, m); sq += __shfl_xor(sq, m); }
  __shared__ float rs[4], rq[4];
  if ((t & 63) == 0) { rs[t >> 6] = s; rq[t >> 6] = sq; }
  __syncthreads();
  s = rs[0] + rs[1] + rs[2] + rs[3];
  sq = rq[0] + rq[1] + rq[2] + rq[3];
  float mu = s * (1.f / MD);
  float var = sq * (1.f / MD) - mu * mu;
  float rstd = rsqrtf(var + 1e-5f);
  f32x2 g2 = *(const f32x2*)&gamma[2 * t];
  f32x2 b2 = *(const f32x2*)&beta[2 * t];
  f32x2 o;
  o[0] = (v0 - mu) * rstd * g2[0] + b2[0];
  o[1] = (v1 - mu) * rstd * g2[1] + b2[1];
  *(f32x2*)&out[base] = o;
}

// ============================================================================
extern "C" void kernel_launch(void* const* d_in, const int* in_sizes, int n_in,
                              void* d_out, int out_size, void* d_ws, size_t ws_size,
                              hipStream_t stream) {
  const float* x     = (const float*)d_in[0];
  const int*   adj   = (const int*)d_in[1];
  const float* W     = (const float*)d_in[2];
  const float* Wb    = (const float*)d_in[3];
  const float* gamma = (const float*)d_in[4];
  const float* beta  = (const float*)d_in[5];
  float* out = (float*)d_out;

  unsigned short* xb  = (unsigned short*)d_ws;              // 4 MB
  unsigned short* wt  = xb + XB_ELEMS;                      // 0.5 MB
  unsigned short* h_c = wt + WT_ELEMS;                      // 4 MB
  unsigned short* h_v = h_c + HH_ELEMS;                     // 4 MB
  unsigned long long* mbits = (unsigned long long*)(h_v + HH_ELEMS);  // 1 MB
  float* l_part = (float*)(mbits + MB_ELEMS);               // 1 MB (8 partials)
  float* o_acc = l_part + NSPLIT_S * L_ELEMS;               // 8.4 MB fp32

  hipMemsetAsync(o_acc, 0, (size_t)O_ELEMS * sizeof(float), stream);
  cvt_kernel<<<2304, 256, 0, stream>>>(x, W, xb, wt);
  maskpack_kernel<<<8192, 1024, 0, stream>>>(adj, mbits);
  proj_kernel<<<dim3(64, 8), 256, 0, stream>>>(xb, wt, Wb, h_c, h_v);
  stats_kernel<<<dim3(128, NSPLIT_S), 512, 0, stream>>>(h_c, mbits, l_part);
  attn_kernel<<<dim3(128, NSPLIT_A), 512, 0, stream>>>(h_c, h_v, mbits, l_part, o_acc,
                                                       out + (size_t)NTOK * MD);
  ln_kernel<<<NTOK, 256, 0, stream>>>(o_acc, gamma, beta, out);
}

// Round 9
// 184.761 us; speedup vs baseline: 2.0260x; 2.0260x over previous
//
#include <hip/hip_runtime.h>

typedef __attribute__((ext_vector_type(8))) short bf16x8;
typedef __attribute__((ext_vector_type(4))) short bf16x4;
typedef __attribute__((ext_vector_type(4))) float f32x4;
typedef __attribute__((ext_vector_type(2))) float f32x2;
typedef __attribute__((ext_vector_type(4))) _Float16 f16x4;
typedef __attribute__((ext_vector_type(2))) _Float16 f16x2;

static __device__ __forceinline__ f32x4 MFMA_QK(bf16x8 a, bf16x8 b, f32x4 c) {
  return __builtin_amdgcn_mfma_f32_16x16x32_bf16(a, b, c, 0, 0, 0);
}

#if __has_builtin(__builtin_amdgcn_mfma_f32_16x16x16bf16_1k)
static __device__ __forceinline__ f32x4 MFMA_PV(bf16x4 a, bf16x4 b, f32x4 c) {
  return __builtin_amdgcn_mfma_f32_16x16x16bf16_1k(a, b, c, 0, 0, 0);
}
#define PV_EPILOGUE_GUARD()
#else
static __device__ __forceinline__ f32x4 MFMA_PV(bf16x4 a, bf16x4 b, f32x4 c) {
  asm("v_mfma_f32_16x16x16_bf16 %0, %1, %2, %0" : "+v"(c) : "v"(a), "v"(b));
  return c;
}
#define PV_EPILOGUE_GUARD() asm volatile("s_nop 7\ns_nop 7" :::)
#endif

#if __has_builtin(__builtin_amdgcn_exp2f)
#define EXP2(x) __builtin_amdgcn_exp2f(x)
#else
#define EXP2(x) exp2f(x)
#endif

#define NB   2
#define NSEQ 2048
#define NH   8
#define ND   64
#define FIN  512
#define MD   512
#define NTOK (NB * NSEQ)
#define SCALE_LOG2E 0.18033688011112042f   // (1/sqrt(64)) * log2(e)

#define XB_ELEMS   (NTOK * FIN)            // 2097152 bf16
#define WT_ELEMS   (MD * FIN)              // 262144 bf16
#define HH_ELEMS   (NB * NH * NSEQ * ND)   // 2097152 bf16 (h_c / h_v each)
#define MB_ELEMS   (NTOK * 32)             // 131072 u64 (bit-packed adj)
#define L_ELEMS    (NB * NH * NSEQ)        // 32768 fp32 per partial
#define O_ELEMS    (NTOK * MD)             // 2097152 f16 per partial
#define NSPLIT_S   8
#define NSPLIT_A   4

static __device__ __forceinline__ unsigned short f2b(float f) {
  union { float f; unsigned u; } c; c.f = f;
  unsigned u = c.u;
  u += 0x7fffu + ((u >> 16) & 1u);   // RNE; inputs finite
  return (unsigned short)(u >> 16);
}

static __device__ __forceinline__ unsigned pack2(float a, float b) {
#if __has_builtin(__builtin_amdgcn_cvt_pk_bf16_f32)
  auto v = __builtin_amdgcn_cvt_pk_bf16_f32(a, b);
  unsigned r; __builtin_memcpy(&r, &v, 4); return r;
#else
  return (unsigned)f2b(a) | ((unsigned)f2b(b) << 16);
#endif
}

static __device__ __forceinline__ void split8(bf16x8 v, bf16x4* a, bf16x4* b) {
  union { bf16x8 w; bf16x4 h[2]; } u; u.w = v; *a = u.h[0]; *b = u.h[1];
}

// ============================================================================
// Convert x -> bf16 (xb) and W -> bf16 transposed (wt[n][k]).
// ============================================================================
__global__ __launch_bounds__(256)
void cvt_kernel(const float* __restrict__ x, const float* __restrict__ W,
                unsigned short* __restrict__ xb, unsigned short* __restrict__ wt) {
  const int t = threadIdx.x;
  if (blockIdx.x < 2048) {
    size_t i = ((size_t)blockIdx.x * 256 + t) * 4;
    f32x4 v = *(const f32x4*)(x + i);
    ushort4 o = make_ushort4(f2b(v[0]), f2b(v[1]), f2b(v[2]), f2b(v[3]));
    *(ushort4*)(xb + i) = o;
  } else {
    int j = ((int)(blockIdx.x - 2048) * 256 + t) * 4;
    int k = j >> 9, n = j & 511;
    f32x4 v = *(const f32x4*)(W + (size_t)k * MD + n);
    wt[(size_t)(n + 0) * FIN + k] = f2b(v[0]);
    wt[(size_t)(n + 1) * FIN + k] = f2b(v[1]);
    wt[(size_t)(n + 2) * FIN + k] = f2b(v[2]);
    wt[(size_t)(n + 3) * FIN + k] = f2b(v[3]);
  }
}

// ============================================================================
// Bit-pack adj: mb[row*32 + w] = ballot(adj[row][w*64 + lane] != 0).
// ============================================================================
__global__ __launch_bounds__(1024)
void maskpack_kernel(const int* __restrict__ adj, unsigned long long* __restrict__ mb) {
  const int t = threadIdx.x;
  const int gw = blockIdx.x * 16 + (t >> 6);     // gw = row*32 + w64
  const int row = gw >> 5, w64 = gw & 31;
  int a = adj[(size_t)row * NSEQ + w64 * 64 + (t & 63)];
  unsigned long long m = __ballot(a != 0);
  if ((t & 63) == 0) mb[gw] = m;
}

// ============================================================================
// Projection GEMM -> h in MFMA-fragment layouts. Dual accumulators (r8-proven):
//  acc_v = MFMA(af, bf): lane holds 4 consecutive TOKENS for fixed d -> h_v
//  acc_c = MFMA(bf, af): lane holds 4 consecutive D for fixed token -> h_c
// Both epilogues are pure ushort4 coalesced stores (no scalar scatter).
// ============================================================================
__global__ __launch_bounds__(256, 2)
void proj_kernel(const unsigned short* __restrict__ xb, const unsigned short* __restrict__ wt,
                 const float* __restrict__ bias,
                 unsigned short* __restrict__ h_c, unsigned short* __restrict__ h_v) {
  __shared__ __align__(16) unsigned short sA[64][72];
  __shared__ __align__(16) unsigned short sB[64][72];
  const int t = threadIdx.x;
  const int w = t >> 6, L = t & 63, l15 = L & 15, qd = L >> 4;
  const int bm = blockIdx.x, bn = blockIdx.y;
  const int r = t >> 3, c8 = (t & 7) * 8;
  const f32x4 ZERO4 = {0.f, 0.f, 0.f, 0.f};

  f32x4 acc_v[4], acc_c[4];
  #pragma unroll
  for (int q = 0; q < 4; ++q) { acc_v[q] = ZERO4; acc_c[q] = ZERO4; }

  for (int ks = 0; ks < FIN; ks += 64) {
    __syncthreads();
    *(bf16x8*)&sA[r][c8]      = *(const bf16x8*)&xb[(size_t)(bm*64 + r)      * FIN + ks + c8];
    *(bf16x8*)&sA[r + 32][c8] = *(const bf16x8*)&xb[(size_t)(bm*64 + r + 32) * FIN + ks + c8];
    *(bf16x8*)&sB[r][c8]      = *(const bf16x8*)&wt[(size_t)(bn*64 + r)      * FIN + ks + c8];
    *(bf16x8*)&sB[r + 32][c8] = *(const bf16x8*)&wt[(size_t)(bn*64 + r + 32) * FIN + ks + c8];
    __syncthreads();
    #pragma unroll
    for (int kk = 0; kk < 2; ++kk) {
      bf16x8 af = *(const bf16x8*)&sA[16*w + l15][kk*32 + qd*8];
      #pragma unroll
      for (int q = 0; q < 4; ++q) {
        bf16x8 bf = *(const bf16x8*)&sB[16*q + l15][kk*32 + qd*8];
        acc_v[q] = MFMA_QK(af, bf, acc_v[q]);
        acc_c[q] = MFMA_QK(bf, af, acc_c[q]);
      }
    }
  }

  const int head = bn;
  const int b0 = bm >> 5;
  const int nloc = (bm & 31) * 64;               // token base within batch b0
  const size_t slab = (size_t)(b0 * NH + head) * ((size_t)NSEQ * ND);

  // h_v: acc_v[q][rr] = h[token = nloc+16w+qd*4+rr][d = 16q+l15]
  #pragma unroll
  for (int q = 0; q < 4; ++q) {
    int d = 16*q + l15;
    float bv = bias[bn*64 + d];
    unsigned short pk[4];
    #pragma unroll
    for (int rr = 0; rr < 4; ++rr) pk[rr] = f2b(acc_v[q][rr] + bv);
    int n0 = nloc + 16*w + qd*4;
    size_t vidx = slab + (size_t)(n0 >> 4) * 1024 + (size_t)(d >> 5) * 512
                + (size_t)((((n0 >> 2) & 3) * 16 + (d & 15)) * 8) + (size_t)(((d >> 4) & 1) * 4);
    *(ushort4*)&h_v[vidx] = make_ushort4(pk[0], pk[1], pk[2], pk[3]);
  }
  // h_c: acc_c[q][rr] = h[token = nloc+16w+l15][d = 16q+4qd+rr]
  #pragma unroll
  for (int q = 0; q < 4; ++q) {
    int dbase = 16*q + 4*qd;
    f32x4 bv4 = *(const f32x4*)&bias[bn*64 + dbase];
    unsigned short pk[4];
    #pragma unroll
    for (int rr = 0; rr < 4; ++rr) pk[rr] = f2b(acc_c[q][rr] + bv4[rr]);
    int n = nloc + 16*w + l15;
    size_t cidx = slab + (size_t)(n >> 4) * 1024 + (size_t)(q >> 1) * 512
                + (size_t)(((dbase >> 3) & 3) * 128) + (size_t)((n & 15) * 8) + (size_t)(dbase & 7);
    *(ushort4*)&h_c[cidx] = make_ushort4(pk[0], pk[1], pk[2], pk[3]);
  }
}

// ============================================================================
// Stats: l_part[e][b][h][n] = sum over column-eighth e of mask*exp(s/8).
// No LDS, no barriers; all loads lane-contiguous from h_c. Grid (128,8).
// ============================================================================
__global__ __launch_bounds__(512, 4)
void stats_kernel(const unsigned short* __restrict__ h_c,
                  const unsigned long long* __restrict__ mb,
                  float* __restrict__ l_part) {
  const int t = threadIdx.x;
  const int h = t >> 6, L = t & 63, l15 = L & 15, qd = L >> 4;
  const int u = blockIdx.x & 7;
  const int b = u >> 2;
  const int rblk = ((int)blockIdx.x >> 3) * 4 + (u & 3);
  const int q8 = blockIdx.y;
  const int n0 = rblk * 32;
  const int qd4 = qd * 4;
  const int lane8 = L * 8;
  const f32x4 ZERO4 = {0.f, 0.f, 0.f, 0.f};

  const unsigned short* hc = h_c + (size_t)(b * NH + h) * (NSEQ * ND);
  bf16x8 qf[2][2];
  #pragma unroll
  for (int g = 0; g < 2; ++g)
    #pragma unroll
    for (int kk = 0; kk < 2; ++kk)
      qf[g][kk] = *(const bf16x8*)&hc[((n0 >> 4) + g) * 1024 + kk * 512 + lane8];

  float lacc[2] = {0.f, 0.f};
  const unsigned long long* mrow = mb + (((size_t)(b * NSEQ + n0 + l15)) << 5) + q8 * 4;

  for (int it = 0; it < 4; ++it) {
    const int c0 = q8 * 256 + it * 64;
    unsigned mlo[2], mhi[2];
    #pragma unroll
    for (int g = 0; g < 2; ++g) {
      unsigned long long m = mrow[g * 512 + it];   // row += 16 -> +512 u64
      mlo[g] = (unsigned)m; mhi[g] = (unsigned)(m >> 32);
    }
    #pragma unroll
    for (int cc = 0; cc < 4; ++cc) {
      const int cb = (c0 >> 4) + cc;
      bf16x8 kf0 = *(const bf16x8*)&hc[cb * 1024 + lane8];
      bf16x8 kf1 = *(const bf16x8*)&hc[cb * 1024 + 512 + lane8];
      #pragma unroll
      for (int g = 0; g < 2; ++g) {
        f32x4 s = MFMA_QK(kf0, qf[g][0], ZERO4);
        s = MFMA_QK(kf1, qf[g][1], s);
        unsigned nib = (((cc & 2) ? mhi[g] : mlo[g]) >> (((cc & 1) << 4) + qd4)) & 0xFu;
        #pragma unroll
        for (int rr = 0; rr < 4; ++rr) {
          float e = EXP2(s[rr] * SCALE_LOG2E);
          lacc[g] += (nib & (1u << rr)) ? e : 0.f;
        }
      }
    }
  }
  #pragma unroll
  for (int g = 0; g < 2; ++g) {
    float v = lacc[g];
    v += __shfl_xor(v, 16);
    v += __shfl_xor(v, 32);
    if (L < 16)
      l_part[(size_t)q8 * L_ELEMS + (size_t)(b * NH + h) * NSEQ + n0 + g*16 + L] = v;
  }
}

// ============================================================================
// Attention (r7-proven): 32 rows/block, fragment-order loads, double-buffered
// s_part -> ONE barrier/iter, fp16 o_part partials. Grid (128,4), 512 thr.
// launch_bounds (512,4): VGPR cap 128 (r4 lesson). NO global atomics (r8 lesson).
// ============================================================================
__global__ __launch_bounds__(512, 4)
void attn_kernel(const unsigned short* __restrict__ h_c, const unsigned short* __restrict__ h_v,
                 const unsigned long long* __restrict__ mb, const float* __restrict__ l_part,
                 _Float16* __restrict__ o_part, float* __restrict__ mean_out) {
  const int t = threadIdx.x;
  const int h = t >> 6, L = t & 63, l15 = L & 15, qd = L >> 4;
  const int u = blockIdx.x & 7;
  const int b = u >> 2;
  const int rblk = ((int)blockIdx.x >> 3) * 4 + (u & 3);
  const int quarter = blockIdx.y;
  const int n0 = rblk * 32;
  const int qd4 = qd * 4;
  const int lane8 = L * 8;
  __shared__ __align__(16) unsigned short s_part[2][8][32][72];   // 73728 B
  const f32x4 ZERO4 = {0.f, 0.f, 0.f, 0.f};

  const unsigned short* hc = h_c + (size_t)(b * NH + h) * (NSEQ * ND);
  const unsigned short* hv = h_v + (size_t)(b * NH + h) * (NSEQ * ND);

  bf16x8 qf[2][2];
  #pragma unroll
  for (int g = 0; g < 2; ++g)
    #pragma unroll
    for (int kk = 0; kk < 2; ++kk)
      qf[g][kk] = *(const bf16x8*)&hc[((n0 >> 4) + g) * 1024 + kk * 512 + lane8];

  float linv[2];
  #pragma unroll
  for (int g = 0; g < 2; ++g) {
    size_t idx = (size_t)(b * NH + h) * NSEQ + n0 + g*16 + l15;
    float ls = 0.f;
    #pragma unroll
    for (int q = 0; q < NSPLIT_S; ++q) ls += l_part[(size_t)q * L_ELEMS + idx];
    linv[g] = -__log2f(ls);
  }

  f32x4 oacc[2][4];
  #pragma unroll
  for (int g = 0; g < 2; ++g)
    #pragma unroll
    for (int dc = 0; dc < 4; ++dc) oacc[g][dc] = ZERO4;

  const int cr = t >> 4, cc4 = (t & 15) * 4;
  const unsigned long long* mrow = mb + (((size_t)(b * NSEQ + n0 + l15)) << 5) + quarter * 8;

  for (int it = 0; it < 8; ++it) {
    const int c0 = quarter * 512 + it * 64;
    const int buf = it & 1;
    unsigned mlo[2], mhi[2];
    #pragma unroll
    for (int g = 0; g < 2; ++g) {
      unsigned long long m = mrow[g * 512 + it];
      mlo[g] = (unsigned)m; mhi[g] = (unsigned)(m >> 32);
    }
    #pragma unroll
    for (int cc = 0; cc < 4; ++cc) {
      const int cb = (c0 >> 4) + cc;
      bf16x8 kf0 = *(const bf16x8*)&hc[cb * 1024 + lane8];
      bf16x8 kf1 = *(const bf16x8*)&hc[cb * 1024 + 512 + lane8];
      bf16x8 vv0 = *(const bf16x8*)&hv[cb * 1024 + lane8];
      bf16x8 vv1 = *(const bf16x8*)&hv[cb * 1024 + 512 + lane8];
      bf16x4 va[4];
      split8(vv0, &va[0], &va[1]);
      split8(vv1, &va[2], &va[3]);
      #pragma unroll
      for (int g = 0; g < 2; ++g) {
        f32x4 s = MFMA_QK(kf0, qf[g][0], ZERO4);
        s = MFMA_QK(kf1, qf[g][1], s);
        unsigned nib = (((cc & 2) ? mhi[g] : mlo[g]) >> (((cc & 1) << 4) + qd4)) & 0xFu;
        f32x4 p;
        #pragma unroll
        for (int rr = 0; rr < 4; ++rr) {
          float e = EXP2(__builtin_fmaf(s[rr], SCALE_LOG2E, linv[g]));
          p[rr] = (nib & (1u << rr)) ? e : 0.f;
        }
        union { unsigned u2[2]; bf16x4 v4; uint2 d; } pk;
        pk.u2[0] = pack2(p[0], p[1]);
        pk.u2[1] = pack2(p[2], p[3]);
        *(uint2*)&s_part[buf][h][g*16 + l15][cc*16 + qd4] = pk.d;
        #pragma unroll
        for (int dc = 0; dc < 4; ++dc)
          oacc[g][dc] = MFMA_PV(va[dc], pk.v4, oacc[g][dc]);
      }
    }
    __syncthreads();   // s_part[buf] complete; prior reads of other buffer done
    {
      f32x4 macc = ZERO4;
      #pragma unroll
      for (int hh = 0; hh < 8; ++hh) {
        uint2 pv = *(const uint2*)&s_part[buf][hh][cr][cc4];
        union { unsigned u; float f; } a0, a1, a2, a3;
        a0.u = pv.x << 16; a1.u = pv.x & 0xffff0000u;
        a2.u = pv.y << 16; a3.u = pv.y & 0xffff0000u;
        macc[0] += a0.f; macc[1] += a1.f; macc[2] += a2.f; macc[3] += a3.f;
      }
      macc *= 0.125f;
      *(f32x4*)&mean_out[((size_t)b * NSEQ + n0 + cr) * NSEQ + c0 + cc4] = macc;
    }
  }

  PV_EPILOGUE_GUARD();
  #pragma unroll
  for (int g = 0; g < 2; ++g)
    #pragma unroll
    for (int dc = 0; dc < 4; ++dc) {
      size_t token = (size_t)b * NSEQ + n0 + g*16 + l15;
      f16x4 o;
      #pragma unroll
      for (int rr = 0; rr < 4; ++rr) o[rr] = (_Float16)oacc[g][dc][rr];
      *(f16x4*)&o_part[(size_t)quarter * O_ELEMS + token * MD + h*64 + dc*16 + qd4] = o;
    }
}

// ============================================================================
// LayerNorm over model dim; sums the 4 fp16 column-quarter O partials.
// ============================================================================
__global__ __launch_bounds__(256)
void ln_kernel(const _Float16* __restrict__ o_part, const float* __restrict__ gamma,
               const float* __restrict__ beta, float* __restrict__ out) {
  const int row = blockIdx.x, t = threadIdx.x;
  const size_t base = (size_t)row * MD + 2 * t;
  float v0 = 0.f, v1 = 0.f;
  #pragma unroll
  for (int q = 0; q < NSPLIT_A; ++q) {
    f16x2 x = *(const f16x2*)&o_part[(size_t)q * O_ELEMS + base];
    v0 += (float)x[0]; v1 += (float)x[1];
  }
  float s = v0 + v1, sq = v0 * v0 + v1 * v1;
  for (int m = 1; m < 64; m <<= 1) { s += __shfl_xor(s, m); sq += __shfl_xor(sq, m); }
  __shared__ float rs[4], rq[4];
  if ((t & 63) == 0) { rs[t >> 6] = s; rq[t >> 6] = sq; }
  __syncthreads();
  s = rs[0] + rs[1] + rs[2] + rs[3];
  sq = rq[0] + rq[1] + rq[2] + rq[3];
  float mu = s * (1.f / MD);
  float var = sq * (1.f / MD) - mu * mu;
  float rstd = rsqrtf(var + 1e-5f);
  f32x2 g2 = *(const f32x2*)&gamma[2 * t];
  f32x2 b2 = *(const f32x2*)&beta[2 * t];
  f32x2 o;
  o[0] = (v0 - mu) * rstd * g2[0] + b2[0];
  o[1] = (v1 - mu) * rstd * g2[1] + b2[1];
  *(f32x2*)&out[base] = o;
}

// ============================================================================
extern "C" void kernel_launch(void* const* d_in, const int* in_sizes, int n_in,
                              void* d_out, int out_size, void* d_ws, size_t ws_size,
                              hipStream_t stream) {
  const float* x     = (const float*)d_in[0];
  const int*   adj   = (const int*)d_in[1];
  const float* W     = (const float*)d_in[2];
  const float* Wb    = (const float*)d_in[3];
  const float* gamma = (const float*)d_in[4];
  const float* beta  = (const float*)d_in[5];
  float* out = (float*)d_out;

  unsigned short* xb  = (unsigned short*)d_ws;              // 4 MB
  unsigned short* wt  = xb + XB_ELEMS;                      // 0.5 MB
  unsigned short* h_c = wt + WT_ELEMS;                      // 4 MB
  unsigned short* h_v = h_c + HH_ELEMS;                     // 4 MB
  unsigned long long* mbits = (unsigned long long*)(h_v + HH_ELEMS);  // 1 MB
  float* l_part = (float*)(mbits + MB_ELEMS);               // 1 MB (8 partials)
  _Float16* o_part = (_Float16*)(l_part + NSPLIT_S * L_ELEMS);  // 16 MB (4 partials)

  cvt_kernel<<<2304, 256, 0, stream>>>(x, W, xb, wt);
  maskpack_kernel<<<8192, 1024, 0, stream>>>(adj, mbits);
  proj_kernel<<<dim3(64, 8), 256, 0, stream>>>(xb, wt, Wb, h_c, h_v);
  stats_kernel<<<dim3(128, NSPLIT_S), 512, 0, stream>>>(h_c, mbits, l_part);
  attn_kernel<<<dim3(128, NSPLIT_A), 512, 0, stream>>>(h_c, h_v, mbits, l_part, o_part,
                                                       out + (size_t)NTOK * MD);
  ln_kernel<<<NTOK, 256, 0, stream>>>(o_part, gamma, beta, out);
}